// Round 1
// baseline (576.418 us; speedup 1.0000x reference)
//
#include <hip/hip_runtime.h>
#include <hip/hip_bf16.h>
#include <stdint.h>

// AFT-full, MI355X. Shapes: x[64,1024,512], W*[512,512], pos_bias[1024,1024].
//   q,k,v = x W^T + b ; out = sigmoid(q) * (eb@(e^k*v)) / (eb@e^k), eb=exp(pos_bias)
// Pipeline:
//   K0: eb = bf16(exp(pos_bias))                      [1024,1024]
//   P1: fused QKV GEMM (bf16 MFMA, fp32 acc):
//        s   = bf16(sigmoid(q))  natural [b,j,d]
//        ekT = bf16(exp(k))      transposed [b][d][j]
//        vT  = bf16(v)           transposed [b][d][j]
//   P2: per-batch GEMM C[i,d]: num=eb@(ek*v), den=eb@ek (dual acc, ekv computed
//       during staging), epilogue out = s*num/den (fp32).
// Workspace: eb 2MiB @0, s 64MiB @4MiB, ekT 64MiB @68MiB, vT 64MiB @132MiB.

#define NSEQ 1024
#define DM   512

typedef __attribute__((ext_vector_type(8))) short bf16x8;
typedef __attribute__((ext_vector_type(4))) float f32x4;

static __device__ __forceinline__ float b2f(unsigned short u) {
    union { uint32_t i; float f; } c; c.i = ((uint32_t)u) << 16; return c.f;
}
// round-to-nearest-even fp32 -> bf16 (inputs finite)
static __device__ __forceinline__ unsigned short f2b(float f) {
    union { float f; uint32_t i; } c; c.f = f;
    uint32_t r = c.i + 0x7FFFu + ((c.i >> 16) & 1u);
    return (unsigned short)(r >> 16);
}

__global__ void k_eb(const float* __restrict__ pb, unsigned short* __restrict__ eb) {
    int i = blockIdx.x * 256 + threadIdx.x;           // one float4 per thread
    float4 v = reinterpret_cast<const float4*>(pb)[i];
    union { unsigned short u[4]; uint2 p; } o;
    o.u[0] = f2b(expf(v.x)); o.u[1] = f2b(expf(v.y));
    o.u[2] = f2b(expf(v.z)); o.u[3] = f2b(expf(v.w));
    reinterpret_cast<uint2*>(eb)[i] = o.p;
}

// ---------------- P1: fused QKV projection ----------------
// Grid (512, 12): x = m-tile (M=65536/128), y = e-tile (E=1536/128; 0-3 q, 4-7 k, 8-11 v)
__launch_bounds__(256)
__global__ void k_qkv(const float* __restrict__ x,
                      const float* __restrict__ Wq, const float* __restrict__ bq,
                      const float* __restrict__ Wk, const float* __restrict__ bk,
                      const float* __restrict__ Wv, const float* __restrict__ bv,
                      unsigned short* __restrict__ s_out,
                      unsigned short* __restrict__ ekT,
                      unsigned short* __restrict__ vT)
{
    __shared__ unsigned short smem[2 * 128 * 72];     // As | Bs, 36864 B
    unsigned short* As = smem;                        // [128][72] bf16, k-contig rows
    unsigned short* Bs = smem + 128 * 72;

    const int tid  = threadIdx.x;
    const int brow = blockIdx.x * 128;                // global m
    const int bcol = blockIdx.y * 128;                // global e in [0,1536)
    const int sel  = bcol >> 9;                       // 0=q 1=k 2=v
    const float* W    = (sel == 0) ? Wq : (sel == 1) ? Wk : Wv;
    const float* bias = (sel == 0) ? bq : (sel == 1) ? bk : bv;
    const int ecol = bcol & 511;                      // col within this W

    const int lane = tid & 63, wave = tid >> 6;
    const int wr = wave >> 1, wc = wave & 1;          // 2x2 waves, 64x64 each
    const int lrow = lane & 15, lkg = lane >> 4;

    f32x4 acc[4][4];
    const f32x4 z4 = {0.f, 0.f, 0.f, 0.f};
    #pragma unroll
    for (int a = 0; a < 4; ++a)
        #pragma unroll
        for (int b = 0; b < 4; ++b) acc[a][b] = z4;

    for (int kt = 0; kt < DM; kt += 64) {
        // stage A (x fp32 -> bf16) and B (W fp32 -> bf16): 128x64 each
        #pragma unroll
        for (int it = 0; it < 4; ++it) {
            int idx = it * 256 + tid;
            int r = idx >> 3, cg = idx & 7;
            {
                const float4* pa = reinterpret_cast<const float4*>(
                    x + (size_t)(brow + r) * DM + kt + cg * 8);
                float4 f0 = pa[0], f1 = pa[1];
                union { unsigned short u[8]; int4 v; } p;
                p.u[0]=f2b(f0.x); p.u[1]=f2b(f0.y); p.u[2]=f2b(f0.z); p.u[3]=f2b(f0.w);
                p.u[4]=f2b(f1.x); p.u[5]=f2b(f1.y); p.u[6]=f2b(f1.z); p.u[7]=f2b(f1.w);
                *reinterpret_cast<int4*>(&As[r * 72 + cg * 8]) = p.v;
            }
            {
                const float4* pw = reinterpret_cast<const float4*>(
                    W + (size_t)(ecol + r) * DM + kt + cg * 8);
                float4 f0 = pw[0], f1 = pw[1];
                union { unsigned short u[8]; int4 v; } p;
                p.u[0]=f2b(f0.x); p.u[1]=f2b(f0.y); p.u[2]=f2b(f0.z); p.u[3]=f2b(f0.w);
                p.u[4]=f2b(f1.x); p.u[5]=f2b(f1.y); p.u[6]=f2b(f1.z); p.u[7]=f2b(f1.w);
                *reinterpret_cast<int4*>(&Bs[r * 72 + cg * 8]) = p.v;
            }
        }
        __syncthreads();
        #pragma unroll
        for (int kk = 0; kk < 2; ++kk) {
            bf16x8 af[4], bfr[4];
            #pragma unroll
            for (int mi = 0; mi < 4; ++mi)
                af[mi] = *reinterpret_cast<const bf16x8*>(
                    &As[(wr*64 + mi*16 + lrow) * 72 + kk*32 + lkg*8]);
            #pragma unroll
            for (int ni = 0; ni < 4; ++ni)
                bfr[ni] = *reinterpret_cast<const bf16x8*>(
                    &Bs[(wc*64 + ni*16 + lrow) * 72 + kk*32 + lkg*8]);
            #pragma unroll
            for (int mi = 0; mi < 4; ++mi)
                #pragma unroll
                for (int ni = 0; ni < 4; ++ni)
                    acc[mi][ni] = __builtin_amdgcn_mfma_f32_16x16x32_bf16(
                        af[mi], bfr[ni], acc[mi][ni], 0, 0, 0);
        }
        __syncthreads();
    }

    // epilogue: re-layout through LDS.  T overlays As/Bs (17408 <= 18432 ushorts)
    unsigned short* T = smem;                          // [128][136]
    if (sel == 0) {
        // T[m][n] = sigmoid(q); store natural [b,j,d]
        #pragma unroll
        for (int mi = 0; mi < 4; ++mi) {
            int m0 = wr*64 + mi*16 + lkg*4;
            #pragma unroll
            for (int ni = 0; ni < 4; ++ni) {
                int n = wc*64 + ni*16 + lrow;
                float bia = bias[ecol + n];
                #pragma unroll
                for (int r = 0; r < 4; ++r) {
                    float t = acc[mi][ni][r] + bia;
                    T[(m0 + r) * 136 + n] = f2b(1.f / (1.f + expf(-t)));
                }
            }
        }
        __syncthreads();
        #pragma unroll
        for (int it = 0; it < 8; ++it) {
            int idx = it * 256 + tid;
            int m = idx >> 4, ng = idx & 15;
            int4 vv = *reinterpret_cast<const int4*>(&T[m * 136 + ng * 8]);
            *reinterpret_cast<int4*>(&s_out[(size_t)(brow + m) * DM + bcol + ng * 8]) = vv;
        }
    } else {
        // T[n][m] = exp(k) or v; store transposed [b][d][j]
        const bool isk = (sel == 1);
        #pragma unroll
        for (int mi = 0; mi < 4; ++mi) {
            int m0 = wr*64 + mi*16 + lkg*4;
            #pragma unroll
            for (int ni = 0; ni < 4; ++ni) {
                int n = wc*64 + ni*16 + lrow;
                float bia = bias[ecol + n];
                union { unsigned short u[4]; uint2 p; } o;
                #pragma unroll
                for (int r = 0; r < 4; ++r) {
                    float t = acc[mi][ni][r] + bia;
                    o.u[r] = f2b(isk ? expf(t) : t);
                }
                *reinterpret_cast<uint2*>(&T[n * 136 + m0]) = o.p;
            }
        }
        __syncthreads();
        unsigned short* dst = isk ? ekT : vT;
        const size_t base = (size_t)(brow >> 10) * (DM * NSEQ);
        const int j0 = brow & (NSEQ - 1);
        #pragma unroll
        for (int it = 0; it < 8; ++it) {
            int idx = it * 256 + tid;
            int dr = idx >> 4, jg = idx & 15;
            int4 vv = *reinterpret_cast<const int4*>(&T[dr * 136 + jg * 8]);
            *reinterpret_cast<int4*>(&dst[base + (size_t)(ecol + dr) * NSEQ + j0 + jg * 8]) = vv;
        }
    }
}

// ---------------- P2: per-batch mixing GEMM + fused epilogue ----------------
// Grid (8, 8, 64): x = i-tile (1024/128), y = d-tile (512/64), z = batch
__launch_bounds__(256)
__global__ void k_aft(const unsigned short* __restrict__ eb,
                      const unsigned short* __restrict__ ekT,
                      const unsigned short* __restrict__ vT,
                      const unsigned short* __restrict__ s_in,
                      float* __restrict__ out)
{
    __shared__ unsigned short smem[128*72 + 2*64*72]; // Aeb | Bek | Bev, 36864 B
    unsigned short* Aeb = smem;                       // [128][72]
    unsigned short* Bek = smem + 128*72;              // [64][72]
    unsigned short* Bev = smem + 128*72 + 64*72;      // [64][72] (ek*v)

    const int tid = threadIdx.x;
    const int i0 = blockIdx.x * 128;
    const int d0 = blockIdx.y * 64;
    const int b  = blockIdx.z;

    const int lane = tid & 63, wave = tid >> 6;
    const int wr = wave >> 1, wc = wave & 1;          // wave tile 64i x 32d
    const int lrow = lane & 15, lkg = lane >> 4;

    f32x4 accn[4][2], accd[4][2];
    const f32x4 z4 = {0.f, 0.f, 0.f, 0.f};
    #pragma unroll
    for (int a = 0; a < 4; ++a)
        #pragma unroll
        for (int c = 0; c < 2; ++c) { accn[a][c] = z4; accd[a][c] = z4; }

    const size_t bbase = (size_t)b * DM * NSEQ;

    for (int kt = 0; kt < NSEQ; kt += 64) {
        #pragma unroll
        for (int it = 0; it < 4; ++it) {              // A: eb 128x64
            int idx = it * 256 + tid;
            int r = idx >> 3, cg = idx & 7;
            int4 raw = *reinterpret_cast<const int4*>(
                &eb[(size_t)(i0 + r) * NSEQ + kt + cg * 8]);
            *reinterpret_cast<int4*>(&Aeb[r * 72 + cg * 8]) = raw;
        }
        #pragma unroll
        for (int it = 0; it < 2; ++it) {              // B: ek & ek*v, 64x64 each
            int idx = it * 256 + tid;
            int r = idx >> 3, cg = idx & 7;
            size_t off = bbase + (size_t)(d0 + r) * NSEQ + kt + cg * 8;
            int4 e8 = *reinterpret_cast<const int4*>(&ekT[off]);
            int4 v8 = *reinterpret_cast<const int4*>(&vT[off]);
            *reinterpret_cast<int4*>(&Bek[r * 72 + cg * 8]) = e8;
            union { unsigned short u[8]; int4 v; } pe, pv, po;
            pe.v = e8; pv.v = v8;
            #pragma unroll
            for (int j = 0; j < 8; ++j) po.u[j] = f2b(b2f(pe.u[j]) * b2f(pv.u[j]));
            *reinterpret_cast<int4*>(&Bev[r * 72 + cg * 8]) = po.v;
        }
        __syncthreads();
        #pragma unroll
        for (int kk = 0; kk < 2; ++kk) {
            bf16x8 af[4];
            #pragma unroll
            for (int mi = 0; mi < 4; ++mi)
                af[mi] = *reinterpret_cast<const bf16x8*>(
                    &Aeb[(wr*64 + mi*16 + lrow) * 72 + kk*32 + lkg*8]);
            #pragma unroll
            for (int ni = 0; ni < 2; ++ni) {
                int c = (wc*32 + ni*16 + lrow) * 72 + kk*32 + lkg*8;
                bf16x8 bk8 = *reinterpret_cast<const bf16x8*>(&Bek[c]);
                bf16x8 bv8 = *reinterpret_cast<const bf16x8*>(&Bev[c]);
                #pragma unroll
                for (int mi = 0; mi < 4; ++mi) {
                    accd[mi][ni] = __builtin_amdgcn_mfma_f32_16x16x32_bf16(
                        af[mi], bk8, accd[mi][ni], 0, 0, 0);
                    accn[mi][ni] = __builtin_amdgcn_mfma_f32_16x16x32_bf16(
                        af[mi], bv8, accn[mi][ni], 0, 0, 0);
                }
            }
        }
        __syncthreads();
    }

    // epilogue: out = sigmoid(q) * num / den
    #pragma unroll
    for (int mi = 0; mi < 4; ++mi) {
        int il = wr*64 + mi*16 + lkg*4;
        #pragma unroll
        for (int ni = 0; ni < 2; ++ni) {
            int dl = d0 + wc*32 + ni*16 + lrow;
            #pragma unroll
            for (int r = 0; r < 4; ++r) {
                size_t o = ((size_t)b * NSEQ + i0 + il + r) * DM + dl;
                float sv = b2f(s_in[o]);
                out[o] = sv * accn[mi][ni][r] / accd[mi][ni][r];
            }
        }
    }
}

extern "C" void kernel_launch(void* const* d_in, const int* in_sizes, int n_in,
                              void* d_out, int out_size, void* d_ws, size_t ws_size,
                              hipStream_t stream)
{
    const float* x  = (const float*)d_in[0];
    const float* Wq = (const float*)d_in[1];
    const float* bq = (const float*)d_in[2];
    const float* Wk = (const float*)d_in[3];
    const float* bk = (const float*)d_in[4];
    const float* Wv = (const float*)d_in[5];
    const float* bv = (const float*)d_in[6];
    const float* pb = (const float*)d_in[7];
    float* out = (float*)d_out;

    char* ws = (char*)d_ws;
    unsigned short* eb  = (unsigned short*)(ws);                          // 2 MiB
    unsigned short* s   = (unsigned short*)(ws + ((size_t)4   << 20));    // 64 MiB
    unsigned short* ekT = (unsigned short*)(ws + ((size_t)68  << 20));    // 64 MiB
    unsigned short* vT  = (unsigned short*)(ws + ((size_t)132 << 20));    // 64 MiB

    k_eb <<<1024, 256, 0, stream>>>(pb, eb);
    k_qkv<<<dim3(512, 12), 256, 0, stream>>>(x, Wq, bq, Wk, bk, Wv, bv, s, ekT, vT);
    k_aft<<<dim3(8, 8, 64), 256, 0, stream>>>(eb, ekT, vT, s, out);
}

// Round 2
// 477.481 us; speedup vs baseline: 1.2072x; 1.2072x over previous
//
#include <hip/hip_runtime.h>
#include <hip/hip_bf16.h>
#include <stdint.h>

// AFT-full, MI355X. Shapes: x[64,1024,512], W*[512,512], pos_bias[1024,1024].
//   q,k,v = x W^T + b ; out = sigmoid(q) * (eb@(e^k*v)) / (eb@e^k), eb=exp(pos_bias)
// Pipeline:
//   K0: eb = bf16(exp(pos_bias))                      [1024,1024]
//   K1: xb = bf16(x), Wb = bf16([Wq;Wk;Wv]) [1536][512]
//   P1: fused QKV GEMM (bf16 MFMA, fp32 acc, global_load_lds + slot-swizzle):
//        s   = bf16(sigmoid(q))  natural [b,j,d]
//        ekT = bf16(exp(k))      transposed [b][d][j]
//        vT  = bf16(v)           transposed [b][d][j]
//   P2: per-batch GEMM C[i,d]: num=eb@(ek*v), den=eb@ek (dual acc), epilogue
//       out = s*num/den (fp32).
// Workspace: eb 2MiB@0, Wb 1.5MiB@2MiB, xb 64MiB@4MiB, s@68MiB, ekT@132MiB, vT@196MiB.

#define NSEQ 1024
#define DM   512

typedef __attribute__((ext_vector_type(8))) short bf16x8;
typedef __attribute__((ext_vector_type(4))) float f32x4;

static __device__ __forceinline__ float b2f(unsigned short u) {
    union { uint32_t i; float f; } c; c.i = ((uint32_t)u) << 16; return c.f;
}
// round-to-nearest-even fp32 -> bf16 (inputs finite)
static __device__ __forceinline__ unsigned short f2b(float f) {
    union { float f; uint32_t i; } c; c.f = f;
    uint32_t r = c.i + 0x7FFFu + ((c.i >> 16) & 1u);
    return (unsigned short)(r >> 16);
}

// async global->LDS, 16B per lane; lds dest = wave-uniform base + lane*16
static __device__ __forceinline__ void gl_lds16(const unsigned short* g, unsigned short* l) {
    __builtin_amdgcn_global_load_lds(
        (const __attribute__((address_space(1))) unsigned int*)(g),
        (__attribute__((address_space(3))) unsigned int*)(l), 16, 0, 0);
}

__global__ void k_eb(const float* __restrict__ pb, unsigned short* __restrict__ eb) {
    int i = blockIdx.x * 256 + threadIdx.x;           // one float4 per thread
    float4 v = reinterpret_cast<const float4*>(pb)[i];
    union { unsigned short u[4]; uint2 p; } o;
    o.u[0] = f2b(expf(v.x)); o.u[1] = f2b(expf(v.y));
    o.u[2] = f2b(expf(v.z)); o.u[3] = f2b(expf(v.w));
    reinterpret_cast<uint2*>(eb)[i] = o.p;
}

// fp32 -> bf16, 8 elements/thread
__global__ void k_cvt(const float* __restrict__ src, unsigned short* __restrict__ dst) {
    int i = blockIdx.x * 256 + threadIdx.x;
    const float4* p = reinterpret_cast<const float4*>(src) + (size_t)i * 2;
    float4 f0 = p[0], f1 = p[1];
    union { unsigned short u[8]; int4 v; } o;
    o.u[0]=f2b(f0.x); o.u[1]=f2b(f0.y); o.u[2]=f2b(f0.z); o.u[3]=f2b(f0.w);
    o.u[4]=f2b(f1.x); o.u[5]=f2b(f1.y); o.u[6]=f2b(f1.z); o.u[7]=f2b(f1.w);
    reinterpret_cast<int4*>(dst)[i] = o.v;
}

// ---------------- P1: fused QKV projection ----------------
// 6144 blocks: XCD-swizzled; etile (12) fast, mtile (512) slow.
__launch_bounds__(256)
__global__ void k_qkv(const unsigned short* __restrict__ xb,
                      const unsigned short* __restrict__ Wb,
                      const float* __restrict__ bq, const float* __restrict__ bk,
                      const float* __restrict__ bv,
                      unsigned short* __restrict__ s_out,
                      unsigned short* __restrict__ ekT,
                      unsigned short* __restrict__ vT)
{
    __shared__ unsigned short smem[17408];            // As|Bs (16384) ; T overlay (17408)
    unsigned short* As = smem;                        // [128][64] linear, slot-swizzled
    unsigned short* Bs = smem + 128 * 64;

    const int bid = blockIdx.x;
    const int swz = (bid & 7) * 768 + (bid >> 3);     // bijective: 6144 % 8 == 0
    const int mtile = swz / 12, etile = swz % 12;
    const int brow = mtile * 128;                     // global m
    const int erow = etile * 128;                     // row in Wb [1536][512]
    const int sel  = etile >> 2;                      // 0=q 1=k 2=v
    const int ecol = (etile & 3) * 128;               // col within this W
    const float* bias = (sel == 0) ? bq : (sel == 1) ? bk : bv;

    const int tid = threadIdx.x;
    const int lane = tid & 63, wave = tid >> 6;
    const int wr = wave >> 1, wc = wave & 1;          // 2x2 waves, 64x64 each
    const int lrow = lane & 15, lkg = lane >> 4;

    // staging addressing: chunk c = is*4+wave covers LDS bytes [c*1024, c*1024+1024)
    // lane covers LDS row c*8 + lane/8, slot lane&7 (16B slots, 8 per 128B row)
    // source slot pre-swizzled: gslot = slot ^ (row&7)  (row&7 == (lane>>3)&7)
    const int srow  = (lane >> 3);                    // 0..7 within chunk
    const int gslot = (lane & 7) ^ srow;
    const int sxa   = lane & 7;                       // read-side XOR key (= lrow&7)

    f32x4 acc[4][4];
    const f32x4 z4 = {0.f, 0.f, 0.f, 0.f};
    #pragma unroll
    for (int a = 0; a < 4; ++a)
        #pragma unroll
        for (int b = 0; b < 4; ++b) acc[a][b] = z4;

    const size_t a_base = (size_t)brow * DM;
    const size_t b_base = (size_t)erow * DM;

    for (int kt = 0; kt < DM; kt += 64) {
        #pragma unroll
        for (int is = 0; is < 4; ++is) {
            int c = is * 4 + wave;                    // chunk 0..15
            int row = c * 8 + srow;
            size_t goff = (size_t)row * DM + kt + gslot * 8;
            gl_lds16(xb + a_base + goff, As + c * 512);
            gl_lds16(Wb + b_base + goff, Bs + c * 512);
        }
        __syncthreads();
        #pragma unroll
        for (int kk = 0; kk < 2; ++kk) {
            bf16x8 af[4], bfr[4];
            #pragma unroll
            for (int mi = 0; mi < 4; ++mi)
                af[mi] = *reinterpret_cast<const bf16x8*>(
                    &As[(wr*64 + mi*16 + lrow) * 64 + ((((kk<<2)|lkg) ^ sxa) << 3)]);
            #pragma unroll
            for (int ni = 0; ni < 4; ++ni)
                bfr[ni] = *reinterpret_cast<const bf16x8*>(
                    &Bs[(wc*64 + ni*16 + lrow) * 64 + ((((kk<<2)|lkg) ^ sxa) << 3)]);
            #pragma unroll
            for (int mi = 0; mi < 4; ++mi)
                #pragma unroll
                for (int ni = 0; ni < 4; ++ni)
                    acc[mi][ni] = __builtin_amdgcn_mfma_f32_16x16x32_bf16(
                        af[mi], bfr[ni], acc[mi][ni], 0, 0, 0);
        }
        __syncthreads();
    }

    // epilogue: re-layout through LDS.  T overlays As/Bs ([128][136] = 17408 ush)
    unsigned short* T = smem;
    if (sel == 0) {
        // T[m][n] = sigmoid(q); store natural [b,j,d]
        #pragma unroll
        for (int mi = 0; mi < 4; ++mi) {
            int m0 = wr*64 + mi*16 + lkg*4;
            #pragma unroll
            for (int ni = 0; ni < 4; ++ni) {
                int n = wc*64 + ni*16 + lrow;
                float bia = bias[ecol + n];
                #pragma unroll
                for (int r = 0; r < 4; ++r) {
                    float t = acc[mi][ni][r] + bia;
                    T[(m0 + r) * 136 + n] = f2b(1.f / (1.f + expf(-t)));
                }
            }
        }
        __syncthreads();
        #pragma unroll
        for (int it = 0; it < 8; ++it) {
            int idx = it * 256 + tid;
            int m = idx >> 4, ng = idx & 15;
            int4 vv = *reinterpret_cast<const int4*>(&T[m * 136 + ng * 8]);
            *reinterpret_cast<int4*>(&s_out[(size_t)(brow + m) * DM + ecol + ng * 8]) = vv;
        }
    } else {
        // T[n][m] = exp(k) or v; store transposed [b][d][j]
        const bool isk = (sel == 1);
        #pragma unroll
        for (int mi = 0; mi < 4; ++mi) {
            int m0 = wr*64 + mi*16 + lkg*4;
            #pragma unroll
            for (int ni = 0; ni < 4; ++ni) {
                int n = wc*64 + ni*16 + lrow;
                float bia = bias[ecol + n];
                union { unsigned short u[4]; uint2 p; } o;
                #pragma unroll
                for (int r = 0; r < 4; ++r) {
                    float t = acc[mi][ni][r] + bia;
                    o.u[r] = f2b(isk ? expf(t) : t);
                }
                *reinterpret_cast<uint2*>(&T[n * 136 + m0]) = o.p;
            }
        }
        __syncthreads();
        unsigned short* dst = isk ? ekT : vT;
        const size_t base = (size_t)(brow >> 10) * (DM * NSEQ);
        const int j0 = brow & (NSEQ - 1);
        #pragma unroll
        for (int it = 0; it < 8; ++it) {
            int idx = it * 256 + tid;
            int dr = idx >> 4, jg = idx & 15;
            int4 vv = *reinterpret_cast<const int4*>(&T[dr * 136 + jg * 8]);
            *reinterpret_cast<int4*>(&dst[base + (size_t)(ecol + dr) * NSEQ + j0 + jg * 8]) = vv;
        }
    }
}

// ---------------- P2: per-batch mixing GEMM + fused epilogue ----------------
// Grid (8, 8, 64): x = i-tile (1024/128), y = d-tile (512/64), z = batch
__launch_bounds__(256)
__global__ void k_aft(const unsigned short* __restrict__ eb,
                      const unsigned short* __restrict__ ekT,
                      const unsigned short* __restrict__ vT,
                      const unsigned short* __restrict__ s_in,
                      float* __restrict__ out)
{
    __shared__ unsigned short smem[128*72 + 2*64*72]; // Aeb | Bek | Bev, 36864 B
    unsigned short* Aeb = smem;                       // [128][72]
    unsigned short* Bek = smem + 128*72;              // [64][72]
    unsigned short* Bev = smem + 128*72 + 64*72;      // [64][72] (ek*v)

    const int tid = threadIdx.x;
    const int i0 = blockIdx.x * 128;
    const int d0 = blockIdx.y * 64;
    const int b  = blockIdx.z;

    const int lane = tid & 63, wave = tid >> 6;
    const int wr = wave >> 1, wc = wave & 1;          // wave tile 64i x 32d
    const int lrow = lane & 15, lkg = lane >> 4;

    f32x4 accn[4][2], accd[4][2];
    const f32x4 z4 = {0.f, 0.f, 0.f, 0.f};
    #pragma unroll
    for (int a = 0; a < 4; ++a)
        #pragma unroll
        for (int c = 0; c < 2; ++c) { accn[a][c] = z4; accd[a][c] = z4; }

    const size_t bbase = (size_t)b * DM * NSEQ;

    for (int kt = 0; kt < NSEQ; kt += 64) {
        #pragma unroll
        for (int it = 0; it < 4; ++it) {              // A: eb 128x64
            int idx = it * 256 + tid;
            int r = idx >> 3, cg = idx & 7;
            int4 raw = *reinterpret_cast<const int4*>(
                &eb[(size_t)(i0 + r) * NSEQ + kt + cg * 8]);
            *reinterpret_cast<int4*>(&Aeb[r * 72 + cg * 8]) = raw;
        }
        #pragma unroll
        for (int it = 0; it < 2; ++it) {              // B: ek & ek*v, 64x64 each
            int idx = it * 256 + tid;
            int r = idx >> 3, cg = idx & 7;
            size_t off = bbase + (size_t)(d0 + r) * NSEQ + kt + cg * 8;
            int4 e8 = *reinterpret_cast<const int4*>(&ekT[off]);
            int4 v8 = *reinterpret_cast<const int4*>(&vT[off]);
            *reinterpret_cast<int4*>(&Bek[r * 72 + cg * 8]) = e8;
            union { unsigned short u[8]; int4 v; } pe, pv, po;
            pe.v = e8; pv.v = v8;
            #pragma unroll
            for (int j = 0; j < 8; ++j) po.u[j] = f2b(b2f(pe.u[j]) * b2f(pv.u[j]));
            *reinterpret_cast<int4*>(&Bev[r * 72 + cg * 8]) = po.v;
        }
        __syncthreads();
        #pragma unroll
        for (int kk = 0; kk < 2; ++kk) {
            bf16x8 af[4];
            #pragma unroll
            for (int mi = 0; mi < 4; ++mi)
                af[mi] = *reinterpret_cast<const bf16x8*>(
                    &Aeb[(wr*64 + mi*16 + lrow) * 72 + kk*32 + lkg*8]);
            #pragma unroll
            for (int ni = 0; ni < 2; ++ni) {
                int c = (wc*32 + ni*16 + lrow) * 72 + kk*32 + lkg*8;
                bf16x8 bk8 = *reinterpret_cast<const bf16x8*>(&Bek[c]);
                bf16x8 bv8 = *reinterpret_cast<const bf16x8*>(&Bev[c]);
                #pragma unroll
                for (int mi = 0; mi < 4; ++mi) {
                    accd[mi][ni] = __builtin_amdgcn_mfma_f32_16x16x32_bf16(
                        af[mi], bk8, accd[mi][ni], 0, 0, 0);
                    accn[mi][ni] = __builtin_amdgcn_mfma_f32_16x16x32_bf16(
                        af[mi], bv8, accn[mi][ni], 0, 0, 0);
                }
            }
        }
        __syncthreads();
    }

    // epilogue: out = sigmoid(q) * num / den
    #pragma unroll
    for (int mi = 0; mi < 4; ++mi) {
        int il = wr*64 + mi*16 + lkg*4;
        #pragma unroll
        for (int ni = 0; ni < 2; ++ni) {
            int dl = d0 + wc*32 + ni*16 + lrow;
            #pragma unroll
            for (int r = 0; r < 4; ++r) {
                size_t o = ((size_t)b * NSEQ + i0 + il + r) * DM + dl;
                float sv = b2f(s_in[o]);
                out[o] = sv * accn[mi][ni][r] / accd[mi][ni][r];
            }
        }
    }
}

extern "C" void kernel_launch(void* const* d_in, const int* in_sizes, int n_in,
                              void* d_out, int out_size, void* d_ws, size_t ws_size,
                              hipStream_t stream)
{
    const float* x  = (const float*)d_in[0];
    const float* Wq = (const float*)d_in[1];
    const float* bq = (const float*)d_in[2];
    const float* Wk = (const float*)d_in[3];
    const float* bk = (const float*)d_in[4];
    const float* Wv = (const float*)d_in[5];
    const float* bv = (const float*)d_in[6];
    const float* pb = (const float*)d_in[7];
    float* out = (float*)d_out;

    char* ws = (char*)d_ws;
    unsigned short* eb  = (unsigned short*)(ws);                          // 2 MiB
    unsigned short* Wb  = (unsigned short*)(ws + ((size_t)2   << 20));    // 1.5 MiB
    unsigned short* xb  = (unsigned short*)(ws + ((size_t)4   << 20));    // 64 MiB
    unsigned short* s   = (unsigned short*)(ws + ((size_t)68  << 20));    // 64 MiB
    unsigned short* ekT = (unsigned short*)(ws + ((size_t)132 << 20));    // 64 MiB
    unsigned short* vT  = (unsigned short*)(ws + ((size_t)196 << 20));    // 64 MiB

    k_eb <<<1024, 256, 0, stream>>>(pb, eb);
    k_cvt<<<16384, 256, 0, stream>>>(x,  xb);
    k_cvt<<<128,   256, 0, stream>>>(Wq, Wb);
    k_cvt<<<128,   256, 0, stream>>>(Wk, Wb + 512*512);
    k_cvt<<<128,   256, 0, stream>>>(Wv, Wb + 2*512*512);
    k_qkv<<<6144, 256, 0, stream>>>(xb, Wb, bq, bk, bv, s, ekT, vT);
    k_aft<<<dim3(8, 8, 64), 256, 0, stream>>>(eb, ekT, vT, s, out);
}